// Round 6
// baseline (134.473 us; speedup 1.0000x reference)
//
#include <hip/hip_runtime.h>
#include <hip/hip_bf16.h>
#include <math.h>

namespace {
typedef __attribute__((ext_vector_type(8)))  short  short8;   // 8 bf16 (MFMA A/B frag)
typedef __attribute__((ext_vector_type(4)))  float  floatx4;  // MFMA C/D frag

constexpr int Bc = 16;    // batch
constexpr int DC = 16;    // deep channels
constexpr int ND = 1024;  // deep length
constexpr int C  = 64;    // c_in
constexpr int N  = 4096;  // sequence
constexpr int CO = 128;   // c_out
constexpr int KW = 7;
constexpr int F  = C * KW;     // 448
constexpr int LT = 32;         // l-tile in k2
constexpr int PLD = F + 8;     // 456 bf16/row (912 B, 16B-aligned rows)
constexpr int GPS = 560;       // per-(b,chunk) Gram slot: G0[256] G1[256] s[16] d0[16] dN[16]

// workspace layout (bytes)
constexpr size_t WB_OFF = 0;            // bf16 fc_w: 57344*2 = 114688
constexpr size_t GP_OFF = 131072;       // 16*8*560*4 = 286720 (ends 417792)
constexpr size_t MC_OFF = 417792;       // mc[16*64] f32
constexpr size_t SC_OFF = 421888;       // sc2[16*64] f32 (ends 425984)

constexpr float EXP2_SCALE = 2.8853900817779268f;   // 2/ln2: exp(-2d) = 2^(-d*2/ln2)

__device__ inline unsigned short f2bf(float f) {
    __hip_bfloat16 h = __float2bfloat16(f);      // RNE
    return __builtin_bit_cast(unsigned short, h);
}
__device__ inline float rcpf(float x) { return __builtin_amdgcn_rcpf(x); }

// K0: blocks [0,56): fc_w fp32->bf16.
//     blocks [56,184): per-(b,chunk) Gram partials of deep: G0=sum D_d[t]D_e[t],
//       G1=sum D_d[t]D_e[t+1] (global t<=1022), s=sum_t D_d[t], plus D[:,0], D[:,1023].
__global__ __launch_bounds__(256)
void k0(const float* __restrict__ deep, const float* __restrict__ fcw,
        unsigned short* __restrict__ wb, float* __restrict__ gp)
{
    __shared__ __align__(16) float Dch[DC][132];     // cols 0..128 used
    const int blk = blockIdx.x;
    const int tid = threadIdx.x;

    if (blk < 56) {                                  // fc_w -> bf16
        const int i = (blk * 256 + tid) * 4;         // < 57344
        const float4 v = *(const float4*)(fcw + i);
        ushort4 o;
        o.x = f2bf(v.x); o.y = f2bf(v.y); o.z = f2bf(v.z); o.w = f2bf(v.w);
        *(ushort4*)(wb + i) = o;
        return;
    }
    const int i2 = blk - 56;
    const int b  = i2 >> 3;
    const int ch = i2 & 7;
    const int t0 = ch * 128;
    const int d  = tid >> 4;
    const int e  = tid & 15;
#pragma unroll
    for (int p = 0; p < 9; ++p) {
        const int tt = e + 16 * p;
        if (tt < 129)
            Dch[d][tt] = deep[(b * DC + d) * ND + min(t0 + tt, ND - 1)];
    }
    __syncthreads();
    float a0 = 0.f, a1 = 0.f, as = 0.f;
    const int n1 = (ch == 7) ? 127 : 128;            // G1 needs global t <= 1022
    for (int t = 0; t < 128; ++t) {
        const float vd  = Dch[d][t];
        const float ve  = Dch[e][t];
        const float ve1 = (t < n1) ? Dch[e][t + 1] : 0.f;
        a0 = fmaf(vd, ve, a0);
        a1 = fmaf(vd, ve1, a1);
        as += vd;
    }
    float* gpb = gp + (b * 8 + ch) * GPS;
    gpb[tid] = a0;
    gpb[256 + tid] = a1;
    if (e == 0) {
        gpb[512 + d] = as;
        if (ch == 0) gpb[528 + d] = Dch[d][0];
        if (ch == 7) gpb[544 + d] = Dch[d][127];     // global t=1023
    }
}

// KS: one block per batch. Reduce Gram partials -> per-(b,c) mc (mean part) and
//     sc2 (= GAMA/(var+EPS) * 2/ln2, exp2-folded). Same closed-form as verified R5.
__global__ __launch_bounds__(256)
void ks(const float* __restrict__ gp, const float* __restrict__ conv_w,
        const float* __restrict__ conv_b, float* __restrict__ mcs,
        float* __restrict__ scs)
{
    __shared__ float G0s[256], G1s[256], ss[16], dd0[16], ddN[16], qp[8][64];
    const int b = blockIdx.x, tid = threadIdx.x;
    {
        float a0 = 0.f, a1 = 0.f;
#pragma unroll
        for (int ch = 0; ch < 8; ++ch) {
            const float* gpb = gp + (b * 8 + ch) * GPS;
            a0 += gpb[tid];
            a1 += gpb[256 + tid];
        }
        G0s[tid] = a0; G1s[tid] = a1;
        if (tid < 16) {
            float s = 0.f;
#pragma unroll
            for (int ch = 0; ch < 8; ++ch) s += gp[(b * 8 + ch) * GPS + 512 + tid];
            ss[tid]  = s;
            dd0[tid] = gp[(b * 8 + 0) * GPS + 528 + tid];
            ddN[tid] = gp[(b * 8 + 7) * GPS + 544 + tid];
        }
    }
    __syncthreads();
    const int c = tid & 63, part = tid >> 6;
    float w[DC];
    {
        const float4* wr = (const float4*)(conv_w + c * DC);
#pragma unroll
        for (int p = 0; p < 4; ++p) {
            const float4 v = wr[p];
            w[4 * p] = v.x; w[4 * p + 1] = v.y; w[4 * p + 2] = v.z; w[4 * p + 3] = v.w;
        }
    }
    float q0 = 0.f, q1 = 0.f;
#pragma unroll
    for (int dd = 0; dd < 4; ++dd) {
        const int d = 4 * part + dd;
        float i0 = 0.f, i1 = 0.f;
#pragma unroll
        for (int e = 0; e < DC; ++e) {
            i0 = fmaf(w[e], G0s[d * 16 + e], i0);
            i1 = fmaf(w[e], G1s[d * 16 + e], i1);
        }
        q0 = fmaf(w[d], i0, q0);
        q1 = fmaf(w[d], i1, q1);
    }
    qp[part][c] = q0;
    qp[4 + part][c] = q1;
    __syncthreads();
    if (tid < 64) {
        const float Q0 = qp[0][c] + qp[1][c] + qp[2][c] + qp[3][c];
        const float Q1 = qp[4][c] + qp[5][c] + qp[6][c] + qp[7][c];
        float wS = 0.f, V0 = 0.f, VN = 0.f;
#pragma unroll
        for (int d = 0; d < DC; ++d) {
            wS = fmaf(w[d], ss[d],  wS);
            V0 = fmaf(w[d], dd0[d], V0);
            VN = fmaf(w[d], ddN[d], VN);
        }
        const float cb   = conv_b[c];
        const float mean = wS * (1.f / 1024.f) + cb;
        const float S2   = 2.625f * Q0 + 1.375f * Q1 + 0.6875f * (V0 * V0 + VN * VN)
                         + 8.f * cb * wS + 4096.f * cb * cb;
        const float var  = (S2 - 4096.f * mean * mean) * (1.f / 4095.f);   // ddof=1
        mcs[b * 64 + c] = wS * (1.f / 1024.f);
        scs[b * 64 + c] = (0.5f / (var + 1e-9f)) * EXP2_SCALE;
    }
}

// K2: one block per (b, 32-l tile). Two barriers.
//  A: stage Dw (deep window, 768 B); load w, mc, sc2 per thread.
//  D: per thread (c, 8 l): 6 register V values (96 FMA), interp with compile-time
//     constants (interior) / R5's verified general path (edge waves), taps via
//     native exp2, phi -> LDS.
//  E: MFMA out[o,l] = sum_f wb[o,f] * phi[l,f]  (verified R3/R5 phase 2).
__global__ __launch_bounds__(256, 4)
void k2(const float* __restrict__ deep, const float* __restrict__ conv_w,
        const float* __restrict__ x, const float* __restrict__ mcs,
        const float* __restrict__ scs, const unsigned short* __restrict__ wb,
        float* __restrict__ out)
{
    __shared__ __align__(16) unsigned short phi[LT * PLD];   // 29184 B
    __shared__ __align__(16) float Dw[12 * 16];              // 768 B
    const int b   = blockIdx.y;
    const int l0  = blockIdx.x * LT;
    const int t0  = l0 >> 2;
    const int tid = threadIdx.x;
    const int c   = tid & 63;
    const int seg = tid >> 6;

    // ---- A ----
    if (tid < 192) {                                  // deep window [t0-2, t0+9]
        const int ti = tid >> 4, d = tid & 15;
        const int t = min(max(t0 - 2 + ti, 0), ND - 1);
        Dw[ti * 16 + d] = deep[(b * DC + d) * ND + t];
    }
    float w[DC];
    {
        const float4* wr = (const float4*)(conv_w + c * DC);
#pragma unroll
        for (int p = 0; p < 4; ++p) {
            const float4 v = wr[p];
            w[4 * p] = v.x; w[4 * p + 1] = v.y; w[4 * p + 2] = v.z; w[4 * p + 3] = v.w;
        }
    }
    const float mc  = mcs[b * 64 + c];
    const float sc2 = scs[b * 64 + c];
    __syncthreads();

    // ---- D ----
    {
        const int base = l0 + seg * 8;
        // 6 V values cover every interp tap for this thread's 14-wide window.
        float Vr[6];
#pragma unroll
        for (int m = 0; m < 6; ++m) {
            const float* dr = Dw + (2 * seg + m) * 16;
            float a = 0.f;
#pragma unroll
            for (int d = 0; d < DC; ++d) a = fmaf(w[d], dr[d], a);
            Vr[m] = a;
        }
        const float WA[4] = {0.375f, 0.125f, 0.875f, 0.625f};
        float xsv[14], xvf[14];
        const bool edge = (blockIdx.x == 0 && seg == 0) ||
                          (blockIdx.x == (N / LT - 1) && seg == 3);
        const float* xr = x + (size_t)(b * C + c) * N;
        if (!edge) {
            const float4 x0 = *(const float4*)(xr + base - 4);
            const float4 x1 = *(const float4*)(xr + base);
            const float4 x2 = *(const float4*)(xr + base + 4);
            const float4 x3 = *(const float4*)(xr + base + 8);
            const float xf[16] = {x0.x, x0.y, x0.z, x0.w, x1.x, x1.y, x1.z, x1.w,
                                  x2.x, x2.y, x2.z, x2.w, x3.x, x3.y, x3.z, x3.w};
#pragma unroll
            for (int i = 0; i < 14; ++i) {
                const int r  = (i + 1) & 3;                    // (base-3+i)&3, base%4==0
                const int ma = ((i + 5) >> 2) - 1 + (r >> 1);  // V index rel. tbase
                const float wa = WA[r];
                xsv[i] = (fmaf(wa, Vr[ma], (1.f - wa) * Vr[ma + 1]) - mc) * sc2;
                xvf[i] = xf[1 + i];
            }
        } else {                                       // R5-verified general path
            const int tbase = t0 + 2 * seg - 2;
#pragma unroll
            for (int i = 0; i < 14; ++i) {
                const int j  = base - 3 + i;
                const int ja = (j < 0) ? -j : j;
                const int jr = min(ja, 2 * N - 2 - ja);        // reflect
                const int t  = jr >> 2;
                const int r  = jr & 3;
                const float wa = WA[r];
                int tA = t - 1 + (r >> 1);
                int tB = tA + 1;
                if (tA < 0) { tA = 0; tB = 0; }   // src clipped to 0 -> V[0] exactly
                if (tB > ND - 1) tB = ND - 1;     // src clipped to 1023 -> V[1023]
                const int ia = tA - tbase;
                const int ib = tB - tbase;
                xsv[i] = (wa * Vr[ia] + (1.f - wa) * Vr[ib] - mc) * sc2;
                xvf[i] = xr[jr];
            }
        }
        unsigned short* pcol = phi + c * KW;
#pragma unroll
        for (int li = 0; li < 8; ++li) {
            const float cen = xsv[li + 3];
            float u[KW];
            float s = 0.25f;                  // center tap: d=0 -> loss/4 = 1/4 exactly
            u[3] = 0.25f;
#pragma unroll
            for (int k = 0; k < KW; ++k) {
                if (k == 3) continue;
                const float d = fabsf(xsv[li + k] - cen);     // already * 2/ln2
                const float e = __builtin_amdgcn_exp2f(-d);   // = exp(-2*d_true)
                const float t = 1.f + e;
                const float uk = e * rcpf(t * t);             // = loss/4
                u[k] = uk;
                s += uk;
            }
            const float al = rcpf(s);
            unsigned short* pr = pcol + (seg * 8 + li) * PLD;
#pragma unroll
            for (int k = 0; k < KW; ++k) pr[k] = f2bf(u[k] * al * xvf[li + k]);
        }
    }
    __syncthreads();

    // ---- E: MFMA (verified R3/R5 phase 2) ----
    const int lane = tid & 63;
    const int quad = lane >> 4;
    const int rr   = lane & 15;
    const int o0   = seg * 32;

    floatx4 acc00 = {0.f, 0.f, 0.f, 0.f}, acc01 = acc00, acc10 = acc00, acc11 = acc00;
    const unsigned short* wrow0 = wb + (o0 + rr) * F + quad * 8;
    const unsigned short* wrow1 = wrow0 + 16 * F;
    const unsigned short* prow0 = phi + rr * PLD + quad * 8;
    const unsigned short* prow1 = prow0 + 16 * PLD;

    for (int s = 0; s < F / 32; ++s) {
        const int f0 = 32 * s;
        const short8 a0 = *(const short8*)(wrow0 + f0);
        const short8 a1 = *(const short8*)(wrow1 + f0);
        const short8 b0 = *(const short8*)(prow0 + f0);
        const short8 b1 = *(const short8*)(prow1 + f0);
        acc00 = __builtin_amdgcn_mfma_f32_16x16x32_bf16(a0, b0, acc00, 0, 0, 0);
        acc01 = __builtin_amdgcn_mfma_f32_16x16x32_bf16(a0, b1, acc01, 0, 0, 0);
        acc10 = __builtin_amdgcn_mfma_f32_16x16x32_bf16(a1, b0, acc10, 0, 0, 0);
        acc11 = __builtin_amdgcn_mfma_f32_16x16x32_bf16(a1, b1, acc11, 0, 0, 0);
    }

    float* ob = out + (size_t)(b * CO) * N + l0;
#pragma unroll
    for (int i = 0; i < 4; ++i) {
        const int om = quad * 4 + i;
        ob[(o0 + om) * N      + rr     ] = acc00[i];
        ob[(o0 + om) * N      + 16 + rr] = acc01[i];
        ob[(o0 + 16 + om) * N + rr     ] = acc10[i];
        ob[(o0 + 16 + om) * N + 16 + rr] = acc11[i];
    }
}
} // namespace

extern "C" void kernel_launch(void* const* d_in, const int* in_sizes, int n_in,
                              void* d_out, int out_size, void* d_ws, size_t ws_size,
                              hipStream_t stream)
{
    const float* deep   = (const float*)d_in[0];
    const float* x      = (const float*)d_in[1];
    const float* conv_w = (const float*)d_in[2];
    const float* conv_b = (const float*)d_in[3];
    const float* fc_w   = (const float*)d_in[4];
    float* out = (float*)d_out;

    unsigned short* wbuf = (unsigned short*)((char*)d_ws + WB_OFF);
    float*          gp   = (float*)((char*)d_ws + GP_OFF);
    float*          mcs  = (float*)((char*)d_ws + MC_OFF);
    float*          scs  = (float*)((char*)d_ws + SC_OFF);

    hipLaunchKernelGGL(k0, dim3(56 + 128), dim3(256), 0, stream,
                       deep, fc_w, wbuf, gp);
    hipLaunchKernelGGL(ks, dim3(Bc), dim3(256), 0, stream,
                       gp, conv_w, conv_b, mcs, scs);
    hipLaunchKernelGGL(k2, dim3(N / LT, Bc), dim3(256), 0, stream,
                       deep, conv_w, x, mcs, scs, wbuf, out);
}

// Round 7
// 119.122 us; speedup vs baseline: 1.1289x; 1.1289x over previous
//
#include <hip/hip_runtime.h>
#include <hip/hip_bf16.h>
#include <math.h>

namespace {
typedef __attribute__((ext_vector_type(8)))  short  short8;   // 8 bf16 (MFMA A/B frag)
typedef __attribute__((ext_vector_type(4)))  float  floatx4;  // MFMA C/D frag

constexpr int Bc = 16;    // batch
constexpr int DC = 16;    // deep channels
constexpr int ND = 1024;  // deep length
constexpr int C  = 64;    // c_in
constexpr int N  = 4096;  // sequence
constexpr int CO = 128;   // c_out
constexpr int KW = 7;
constexpr int F  = C * KW;     // 448
constexpr int LT = 32;         // l-tile in k2
constexpr int PLD = F + 8;     // 456 bf16/row (912 B, 16B-aligned rows)
constexpr int GPS = 560;       // per-(b,chunk) Gram slot: G0[256] G1[256] s[16] d0[16] dN[16]
constexpr int NS = F / 32;     // 14 K-steps

// workspace layout (bytes)
constexpr size_t WB_OFF = 0;            // swizzled bf16 fc_w: 7168 short8 = 114688
constexpr size_t GP_OFF = 131072;       // 16*8*560*4 = 286720 (ends 417792)
constexpr size_t MC_OFF = 417792;       // mc[16*64] f32
constexpr size_t SC_OFF = 421888;       // sc2[16*64] f32 (ends 425984)

constexpr float EXP2_SCALE = 2.8853900817779268f;   // 2/ln2: exp(-2d) = 2^(-d*2/ln2)

__device__ inline unsigned short f2bf(float f) {
    __hip_bfloat16 h = __float2bfloat16(f);      // RNE
    return __builtin_bit_cast(unsigned short, h);
}
__device__ inline float rcpf(float x) { return __builtin_amdgcn_rcpf(x); }

// K0: blocks [0,28): fc_w fp32 -> bf16, swizzled fragment-major:
//       g = ((w*14 + s)*2 + t)*64 + lane  holds  fcw[o=32w+16t+(lane&15)][f=32s+8*(lane>>4) ..+7]
//     so phase-E A-fragment loads are 64-lane CONTIGUOUS (1 KiB per instr).
//     blocks [28,156): per-(b,chunk) Gram partials of deep (verified R5/R6).
__global__ __launch_bounds__(256)
void k0(const float* __restrict__ deep, const float* __restrict__ fcw,
        unsigned short* __restrict__ wbs, float* __restrict__ gp)
{
    __shared__ __align__(16) float Dch[DC][132];     // cols 0..128 used
    const int blk = blockIdx.x;
    const int tid = threadIdx.x;

    if (blk < 28) {                                  // fc_w swizzle, 7168 short8 total
        const int g    = blk * 256 + tid;
        const int lane = g & 63;
        const int q    = lane >> 4;
        const int rr   = lane & 15;
        const int rest = g >> 6;                     // [0,112)
        const int t    = rest & 1;
        const int sw   = rest >> 1;                  // [0,56)
        const int s    = sw % NS;
        const int w    = sw / NS;
        const int o    = w * 32 + t * 16 + rr;
        const int f    = s * 32 + q * 8;
        const float4 v0 = *(const float4*)(fcw + o * F + f);
        const float4 v1 = *(const float4*)(fcw + o * F + f + 4);
        short8 h;
        h[0] = (short)f2bf(v0.x); h[1] = (short)f2bf(v0.y);
        h[2] = (short)f2bf(v0.z); h[3] = (short)f2bf(v0.w);
        h[4] = (short)f2bf(v1.x); h[5] = (short)f2bf(v1.y);
        h[6] = (short)f2bf(v1.z); h[7] = (short)f2bf(v1.w);
        ((short8*)wbs)[g] = h;
        return;
    }
    const int i2 = blk - 28;
    const int b  = i2 >> 3;
    const int ch = i2 & 7;
    const int t0 = ch * 128;
    const int d  = tid >> 4;
    const int e  = tid & 15;
#pragma unroll
    for (int p = 0; p < 9; ++p) {
        const int tt = e + 16 * p;
        if (tt < 129)
            Dch[d][tt] = deep[(b * DC + d) * ND + min(t0 + tt, ND - 1)];
    }
    __syncthreads();
    float a0 = 0.f, a1 = 0.f, as = 0.f;
    const int n1 = (ch == 7) ? 127 : 128;            // G1 needs global t <= 1022
    for (int t = 0; t < 128; ++t) {
        const float vd  = Dch[d][t];
        const float ve  = Dch[e][t];
        const float ve1 = (t < n1) ? Dch[e][t + 1] : 0.f;
        a0 = fmaf(vd, ve, a0);
        a1 = fmaf(vd, ve1, a1);
        as += vd;
    }
    float* gpb = gp + (b * 8 + ch) * GPS;
    gpb[tid] = a0;
    gpb[256 + tid] = a1;
    if (e == 0) {
        gpb[512 + d] = as;
        if (ch == 0) gpb[528 + d] = Dch[d][0];
        if (ch == 7) gpb[544 + d] = Dch[d][127];     // global t=1023
    }
}

// KS: one block per batch. Gram partials -> per-(b,c) mc, sc2 (verified R6).
__global__ __launch_bounds__(256)
void ks(const float* __restrict__ gp, const float* __restrict__ conv_w,
        const float* __restrict__ conv_b, float* __restrict__ mcs,
        float* __restrict__ scs)
{
    __shared__ float G0s[256], G1s[256], ss[16], dd0[16], ddN[16], qp[8][64];
    const int b = blockIdx.x, tid = threadIdx.x;
    {
        float a0 = 0.f, a1 = 0.f;
#pragma unroll
        for (int ch = 0; ch < 8; ++ch) {
            const float* gpb = gp + (b * 8 + ch) * GPS;
            a0 += gpb[tid];
            a1 += gpb[256 + tid];
        }
        G0s[tid] = a0; G1s[tid] = a1;
        if (tid < 16) {
            float s = 0.f;
#pragma unroll
            for (int ch = 0; ch < 8; ++ch) s += gp[(b * 8 + ch) * GPS + 512 + tid];
            ss[tid]  = s;
            dd0[tid] = gp[(b * 8 + 0) * GPS + 528 + tid];
            ddN[tid] = gp[(b * 8 + 7) * GPS + 544 + tid];
        }
    }
    __syncthreads();
    const int c = tid & 63, part = tid >> 6;
    float w[DC];
    {
        const float4* wr = (const float4*)(conv_w + c * DC);
#pragma unroll
        for (int p = 0; p < 4; ++p) {
            const float4 v = wr[p];
            w[4 * p] = v.x; w[4 * p + 1] = v.y; w[4 * p + 2] = v.z; w[4 * p + 3] = v.w;
        }
    }
    float q0 = 0.f, q1 = 0.f;
#pragma unroll
    for (int dd = 0; dd < 4; ++dd) {
        const int d = 4 * part + dd;
        float i0 = 0.f, i1 = 0.f;
#pragma unroll
        for (int e = 0; e < DC; ++e) {
            i0 = fmaf(w[e], G0s[d * 16 + e], i0);
            i1 = fmaf(w[e], G1s[d * 16 + e], i1);
        }
        q0 = fmaf(w[d], i0, q0);
        q1 = fmaf(w[d], i1, q1);
    }
    qp[part][c] = q0;
    qp[4 + part][c] = q1;
    __syncthreads();
    if (tid < 64) {
        const float Q0 = qp[0][c] + qp[1][c] + qp[2][c] + qp[3][c];
        const float Q1 = qp[4][c] + qp[5][c] + qp[6][c] + qp[7][c];
        float wS = 0.f, V0 = 0.f, VN = 0.f;
#pragma unroll
        for (int d = 0; d < DC; ++d) {
            wS = fmaf(w[d], ss[d],  wS);
            V0 = fmaf(w[d], dd0[d], V0);
            VN = fmaf(w[d], ddN[d], VN);
        }
        const float cb   = conv_b[c];
        const float mean = wS * (1.f / 1024.f) + cb;
        const float S2   = 2.625f * Q0 + 1.375f * Q1 + 0.6875f * (V0 * V0 + VN * VN)
                         + 8.f * cb * wS + 4096.f * cb * cb;
        const float var  = (S2 - 4096.f * mean * mean) * (1.f / 4095.f);   // ddof=1
        mcs[b * 64 + c] = wS * (1.f / 1024.f);
        scs[b * 64 + c] = (0.5f / (var + 1e-9f)) * EXP2_SCALE;
    }
}

// K2: one block per (b, 32-l tile). Two barriers. Phase D as verified in R6;
// phase E now reads the SWIZZLED wbs (coalesced 1 KiB/instr) with the K-loop
// fully unrolled so loads pipeline instead of waiting per-iteration.
__global__ __launch_bounds__(256, 3)
void k2(const float* __restrict__ deep, const float* __restrict__ conv_w,
        const float* __restrict__ x, const float* __restrict__ mcs,
        const float* __restrict__ scs, const unsigned short* __restrict__ wbs,
        float* __restrict__ out)
{
    __shared__ __align__(16) unsigned short phi[LT * PLD];   // 29184 B
    __shared__ __align__(16) float Dw[12 * 16];              // 768 B
    const int b   = blockIdx.y;
    const int l0  = blockIdx.x * LT;
    const int t0  = l0 >> 2;
    const int tid = threadIdx.x;
    const int c   = tid & 63;
    const int seg = tid >> 6;

    // ---- A ----
    if (tid < 192) {                                  // deep window [t0-2, t0+9]
        const int ti = tid >> 4, d = tid & 15;
        const int t = min(max(t0 - 2 + ti, 0), ND - 1);
        Dw[ti * 16 + d] = deep[(b * DC + d) * ND + t];
    }
    float w[DC];
    {
        const float4* wr = (const float4*)(conv_w + c * DC);
#pragma unroll
        for (int p = 0; p < 4; ++p) {
            const float4 v = wr[p];
            w[4 * p] = v.x; w[4 * p + 1] = v.y; w[4 * p + 2] = v.z; w[4 * p + 3] = v.w;
        }
    }
    const float mc  = mcs[b * 64 + c];
    const float sc2 = scs[b * 64 + c];
    __syncthreads();

    // ---- D ----
    {
        const int base = l0 + seg * 8;
        float Vr[6];                          // covers every interp tap in window
#pragma unroll
        for (int m = 0; m < 6; ++m) {
            const float* dr = Dw + (2 * seg + m) * 16;
            float a = 0.f;
#pragma unroll
            for (int d = 0; d < DC; ++d) a = fmaf(w[d], dr[d], a);
            Vr[m] = a;
        }
        const float WA[4] = {0.375f, 0.125f, 0.875f, 0.625f};
        float xsv[14], xvf[14];
        const bool edge = (blockIdx.x == 0 && seg == 0) ||
                          (blockIdx.x == (N / LT - 1) && seg == 3);
        const float* xr = x + (size_t)(b * C + c) * N;
        if (!edge) {
            const float4 x0 = *(const float4*)(xr + base - 4);
            const float4 x1 = *(const float4*)(xr + base);
            const float4 x2 = *(const float4*)(xr + base + 4);
            const float4 x3 = *(const float4*)(xr + base + 8);
            const float xf[16] = {x0.x, x0.y, x0.z, x0.w, x1.x, x1.y, x1.z, x1.w,
                                  x2.x, x2.y, x2.z, x2.w, x3.x, x3.y, x3.z, x3.w};
#pragma unroll
            for (int i = 0; i < 14; ++i) {
                const int r  = (i + 1) & 3;                    // (base-3+i)&3, base%4==0
                const int ma = ((i + 5) >> 2) - 1 + (r >> 1);  // V index rel. tbase
                const float wa = WA[r];
                xsv[i] = (fmaf(wa, Vr[ma], (1.f - wa) * Vr[ma + 1]) - mc) * sc2;
                xvf[i] = xf[1 + i];
            }
        } else {                                       // verified general path
            const int tbase = t0 + 2 * seg - 2;
#pragma unroll
            for (int i = 0; i < 14; ++i) {
                const int j  = base - 3 + i;
                const int ja = (j < 0) ? -j : j;
                const int jr = min(ja, 2 * N - 2 - ja);        // reflect
                const int t  = jr >> 2;
                const int r  = jr & 3;
                const float wa = WA[r];
                int tA = t - 1 + (r >> 1);
                int tB = tA + 1;
                if (tA < 0) { tA = 0; tB = 0; }   // src clipped to 0 -> V[0] exactly
                if (tB > ND - 1) tB = ND - 1;     // src clipped to 1023 -> V[1023]
                const int ia = tA - tbase;
                const int ib = tB - tbase;
                xsv[i] = (wa * Vr[ia] + (1.f - wa) * Vr[ib] - mc) * sc2;
                xvf[i] = xr[jr];
            }
        }
        unsigned short* pcol = phi + c * KW;
#pragma unroll
        for (int li = 0; li < 8; ++li) {
            const float cen = xsv[li + 3];
            float u[KW];
            float s = 0.25f;                  // center tap: d=0 -> loss/4 = 1/4 exactly
            u[3] = 0.25f;
#pragma unroll
            for (int k = 0; k < KW; ++k) {
                if (k == 3) continue;
                const float d = fabsf(xsv[li + k] - cen);     // already * 2/ln2
                const float e = __builtin_amdgcn_exp2f(-d);   // = exp(-2*d_true)
                const float t = 1.f + e;
                const float uk = e * rcpf(t * t);             // = loss/4
                u[k] = uk;
                s += uk;
            }
            const float al = rcpf(s);
            unsigned short* pr = pcol + (seg * 8 + li) * PLD;
#pragma unroll
            for (int k = 0; k < KW; ++k) pr[k] = f2bf(u[k] * al * xvf[li + k]);
        }
    }
    __syncthreads();

    // ---- E: MFMA, swizzled coalesced A-loads, fully unrolled ----
    const int lane = tid & 63;
    const int quad = lane >> 4;
    const int rr   = lane & 15;
    const int o0   = seg * 32;

    floatx4 acc00 = {0.f, 0.f, 0.f, 0.f}, acc01 = acc00, acc10 = acc00, acc11 = acc00;
    const short8* wp = (const short8*)wbs + (size_t)seg * (NS * 2 * 64) + lane;
    const unsigned short* prow0 = phi + rr * PLD + quad * 8;
    const unsigned short* prow1 = prow0 + 16 * PLD;

#pragma unroll
    for (int s = 0; s < NS; ++s) {
        const int f0 = 32 * s;
        const short8 a0 = wp[s * 128];          // 64 lanes x 16 B contiguous
        const short8 a1 = wp[s * 128 + 64];
        const short8 b0 = *(const short8*)(prow0 + f0);
        const short8 b1 = *(const short8*)(prow1 + f0);
        acc00 = __builtin_amdgcn_mfma_f32_16x16x32_bf16(a0, b0, acc00, 0, 0, 0);
        acc01 = __builtin_amdgcn_mfma_f32_16x16x32_bf16(a0, b1, acc01, 0, 0, 0);
        acc10 = __builtin_amdgcn_mfma_f32_16x16x32_bf16(a1, b0, acc10, 0, 0, 0);
        acc11 = __builtin_amdgcn_mfma_f32_16x16x32_bf16(a1, b1, acc11, 0, 0, 0);
    }

    float* ob = out + (size_t)(b * CO) * N + l0;
#pragma unroll
    for (int i = 0; i < 4; ++i) {
        const int om = quad * 4 + i;
        ob[(o0 + om) * N      + rr     ] = acc00[i];
        ob[(o0 + om) * N      + 16 + rr] = acc01[i];
        ob[(o0 + 16 + om) * N + rr     ] = acc10[i];
        ob[(o0 + 16 + om) * N + 16 + rr] = acc11[i];
    }
}
} // namespace

extern "C" void kernel_launch(void* const* d_in, const int* in_sizes, int n_in,
                              void* d_out, int out_size, void* d_ws, size_t ws_size,
                              hipStream_t stream)
{
    const float* deep   = (const float*)d_in[0];
    const float* x      = (const float*)d_in[1];
    const float* conv_w = (const float*)d_in[2];
    const float* conv_b = (const float*)d_in[3];
    const float* fc_w   = (const float*)d_in[4];
    float* out = (float*)d_out;

    unsigned short* wbuf = (unsigned short*)((char*)d_ws + WB_OFF);
    float*          gp   = (float*)((char*)d_ws + GP_OFF);
    float*          mcs  = (float*)((char*)d_ws + MC_OFF);
    float*          scs  = (float*)((char*)d_ws + SC_OFF);

    hipLaunchKernelGGL(k0, dim3(28 + 128), dim3(256), 0, stream,
                       deep, fc_w, wbuf, gp);
    hipLaunchKernelGGL(ks, dim3(Bc), dim3(256), 0, stream,
                       gp, conv_w, conv_b, mcs, scs);
    hipLaunchKernelGGL(k2, dim3(N / LT, Bc), dim3(256), 0, stream,
                       deep, conv_w, x, mcs, scs, wbuf, out);
}

// Round 8
// 115.664 us; speedup vs baseline: 1.1626x; 1.0299x over previous
//
#include <hip/hip_runtime.h>
#include <hip/hip_bf16.h>
#include <math.h>

namespace {
typedef __attribute__((ext_vector_type(8)))  short  short8;   // 8 bf16 (MFMA A/B frag)
typedef __attribute__((ext_vector_type(4)))  float  floatx4;  // MFMA C/D frag

constexpr int Bc = 16;    // batch
constexpr int DC = 16;    // deep channels
constexpr int ND = 1024;  // deep length
constexpr int C  = 64;    // c_in
constexpr int N  = 4096;  // sequence
constexpr int CO = 128;   // c_out
constexpr int KW = 7;
constexpr int F  = C * KW;     // 448 (true features)
constexpr int F2 = C * 8;      // 512 (padded: f' = c*8+k, k=7 slot is zero)
constexpr int LT = 32;         // l-tile in k2
constexpr int PLD = F2 + 8;    // 520 shorts/row (1040 B, 16B-aligned rows)
constexpr int GPS = 560;       // per-(b,chunk) Gram slot: G0[256] G1[256] s[16] d0[16] dN[16]
constexpr int NS = F2 / 32;    // 16 K-steps

// workspace layout (bytes)
constexpr size_t WB_OFF = 0;            // swizzled bf16 fc_w: 8192 short8 = 262144
constexpr size_t GP_OFF = 262144;       // 16*8*560*4 = 286720 (ends 548864)
constexpr size_t MC_OFF = 548864;       // mc[16*64] f32
constexpr size_t SC_OFF = 552960;       // sc2[16*64] f32 (ends 557056)

constexpr float EXP2_SCALE = 2.8853900817779268f;   // 2/ln2: exp(-2d) = 2^(-d*2/ln2)

__device__ inline unsigned short f2bf(float f) {
    __hip_bfloat16 h = __float2bfloat16(f);      // RNE
    return __builtin_bit_cast(unsigned short, h);
}
__device__ inline float rcpf(float x) { return __builtin_amdgcn_rcpf(x); }

// K0: blocks [0,32): fc_w fp32 -> bf16, zero-padded + swizzled fragment-major:
//       g = ((w*16 + s)*2 + t)*64 + lane holds fcw[o=32w+16t+(lane&15)][c=4s+(lane>>4)][k=0..6], 0
//     so phase-E A-fragment loads are 64-lane CONTIGUOUS (1 KiB per instr) and the
//     k=7 pad slot contributes exactly 0 to the dot product.
//     blocks [32,160): per-(b,chunk) Gram partials of deep (verified R5-R7).
__global__ __launch_bounds__(256)
void k0(const float* __restrict__ deep, const float* __restrict__ fcw,
        unsigned short* __restrict__ wbs, float* __restrict__ gp)
{
    __shared__ __align__(16) float Dch[DC][132];     // cols 0..128 used
    const int blk = blockIdx.x;
    const int tid = threadIdx.x;

    if (blk < 32) {                                  // fc_w swizzle, 8192 short8 total
        const int g    = blk * 256 + tid;
        const int lane = g & 63;
        const int q    = lane >> 4;
        const int rr   = lane & 15;
        const int rest = g >> 6;                     // [0,128)
        const int t    = rest & 1;
        const int sw   = rest >> 1;                  // [0,64)
        const int s    = sw & 15;
        const int w    = sw >> 4;
        const int o    = w * 32 + t * 16 + rr;
        const int c    = s * 4 + q;
        const float* src = fcw + o * F + c * KW;
        const float4 v0 = *(const float4*)(src);       // f0..f3
        const float4 v1 = *(const float4*)(src + 3);   // f3..f6
        short8 h;
        h[0] = (short)f2bf(v0.x); h[1] = (short)f2bf(v0.y);
        h[2] = (short)f2bf(v0.z); h[3] = (short)f2bf(v0.w);
        h[4] = (short)f2bf(v1.y); h[5] = (short)f2bf(v1.z);
        h[6] = (short)f2bf(v1.w); h[7] = 0;            // pad slot (exact no-op)
        ((short8*)wbs)[g] = h;
        return;
    }
    const int i2 = blk - 32;
    const int b  = i2 >> 3;
    const int ch = i2 & 7;
    const int t0 = ch * 128;
    const int d  = tid >> 4;
    const int e  = tid & 15;
#pragma unroll
    for (int p = 0; p < 9; ++p) {
        const int tt = e + 16 * p;
        if (tt < 129)
            Dch[d][tt] = deep[(b * DC + d) * ND + min(t0 + tt, ND - 1)];
    }
    __syncthreads();
    float a0 = 0.f, a1 = 0.f, as = 0.f;
    const int n1 = (ch == 7) ? 127 : 128;            // G1 needs global t <= 1022
    for (int t = 0; t < 128; ++t) {
        const float vd  = Dch[d][t];
        const float ve  = Dch[e][t];
        const float ve1 = (t < n1) ? Dch[e][t + 1] : 0.f;
        a0 = fmaf(vd, ve, a0);
        a1 = fmaf(vd, ve1, a1);
        as += vd;
    }
    float* gpb = gp + (b * 8 + ch) * GPS;
    gpb[tid] = a0;
    gpb[256 + tid] = a1;
    if (e == 0) {
        gpb[512 + d] = as;
        if (ch == 0) gpb[528 + d] = Dch[d][0];
        if (ch == 7) gpb[544 + d] = Dch[d][127];     // global t=1023
    }
}

// KS: one block per batch. Gram partials -> per-(b,c) mc, sc2 (verified R6/R7).
__global__ __launch_bounds__(256)
void ks(const float* __restrict__ gp, const float* __restrict__ conv_w,
        const float* __restrict__ conv_b, float* __restrict__ mcs,
        float* __restrict__ scs)
{
    __shared__ float G0s[256], G1s[256], ss[16], dd0[16], ddN[16], qp[8][64];
    const int b = blockIdx.x, tid = threadIdx.x;
    {
        float a0 = 0.f, a1 = 0.f;
#pragma unroll
        for (int ch = 0; ch < 8; ++ch) {
            const float* gpb = gp + (b * 8 + ch) * GPS;
            a0 += gpb[tid];
            a1 += gpb[256 + tid];
        }
        G0s[tid] = a0; G1s[tid] = a1;
        if (tid < 16) {
            float s = 0.f;
#pragma unroll
            for (int ch = 0; ch < 8; ++ch) s += gp[(b * 8 + ch) * GPS + 512 + tid];
            ss[tid]  = s;
            dd0[tid] = gp[(b * 8 + 0) * GPS + 528 + tid];
            ddN[tid] = gp[(b * 8 + 7) * GPS + 544 + tid];
        }
    }
    __syncthreads();
    const int c = tid & 63, part = tid >> 6;
    float w[DC];
    {
        const float4* wr = (const float4*)(conv_w + c * DC);
#pragma unroll
        for (int p = 0; p < 4; ++p) {
            const float4 v = wr[p];
            w[4 * p] = v.x; w[4 * p + 1] = v.y; w[4 * p + 2] = v.z; w[4 * p + 3] = v.w;
        }
    }
    float q0 = 0.f, q1 = 0.f;
#pragma unroll
    for (int dd = 0; dd < 4; ++dd) {
        const int d = 4 * part + dd;
        float i0 = 0.f, i1 = 0.f;
#pragma unroll
        for (int e = 0; e < DC; ++e) {
            i0 = fmaf(w[e], G0s[d * 16 + e], i0);
            i1 = fmaf(w[e], G1s[d * 16 + e], i1);
        }
        q0 = fmaf(w[d], i0, q0);
        q1 = fmaf(w[d], i1, q1);
    }
    qp[part][c] = q0;
    qp[4 + part][c] = q1;
    __syncthreads();
    if (tid < 64) {
        const float Q0 = qp[0][c] + qp[1][c] + qp[2][c] + qp[3][c];
        const float Q1 = qp[4][c] + qp[5][c] + qp[6][c] + qp[7][c];
        float wS = 0.f, V0 = 0.f, VN = 0.f;
#pragma unroll
        for (int d = 0; d < DC; ++d) {
            wS = fmaf(w[d], ss[d],  wS);
            V0 = fmaf(w[d], dd0[d], V0);
            VN = fmaf(w[d], ddN[d], VN);
        }
        const float cb   = conv_b[c];
        const float mean = wS * (1.f / 1024.f) + cb;
        const float S2   = 2.625f * Q0 + 1.375f * Q1 + 0.6875f * (V0 * V0 + VN * VN)
                         + 8.f * cb * wS + 4096.f * cb * cb;
        const float var  = (S2 - 4096.f * mean * mean) * (1.f / 4095.f);   // ddof=1
        mcs[b * 64 + c] = wS * (1.f / 1024.f);
        scs[b * 64 + c] = (0.5f / (var + 1e-9f)) * EXP2_SCALE;
    }
}

// K2: one block per (b, 32-l tile). Two barriers.
//  A: stage Dw (768 B); per-thread w/mc/sc2; PREFETCH interior x window (4x float4)
//     so the VMEM latency hides under the barrier.
//  D: 6 register V values, interp w/ compile-time constants (interior) or verified
//     general path (2 edge waves); taps via native exp2; phi row written as ONE
//     ds_write_b128 per (c,l) thanks to the k=7 zero pad.
//  E: MFMA over 16 K-steps, swizzled coalesced A-loads (verified R7).
__global__ __launch_bounds__(256, 3)
void k2(const float* __restrict__ deep, const float* __restrict__ conv_w,
        const float* __restrict__ x, const float* __restrict__ mcs,
        const float* __restrict__ scs, const unsigned short* __restrict__ wbs,
        float* __restrict__ out)
{
    __shared__ __align__(16) unsigned short phi[LT * PLD];   // 33280 B
    __shared__ __align__(16) float Dw[12 * 16];              // 768 B
    const int b   = blockIdx.y;
    const int l0  = blockIdx.x * LT;
    const int t0  = l0 >> 2;
    const int tid = threadIdx.x;
    const int c   = tid & 63;
    const int seg = tid >> 6;

    // ---- A ----
    if (tid < 192) {                                  // deep window [t0-2, t0+9]
        const int ti = tid >> 4, d = tid & 15;
        const int t = min(max(t0 - 2 + ti, 0), ND - 1);
        Dw[ti * 16 + d] = deep[(b * DC + d) * ND + t];
    }
    float w[DC];
    {
        const float4* wr = (const float4*)(conv_w + c * DC);
#pragma unroll
        for (int p = 0; p < 4; ++p) {
            const float4 v = wr[p];
            w[4 * p] = v.x; w[4 * p + 1] = v.y; w[4 * p + 2] = v.z; w[4 * p + 3] = v.w;
        }
    }
    const float mc  = mcs[b * 64 + c];
    const float sc2 = scs[b * 64 + c];

    const int base = l0 + seg * 8;
    const bool edge = (blockIdx.x == 0 && seg == 0) ||
                      (blockIdx.x == (N / LT - 1) && seg == 3);
    const float* xr = x + (size_t)(b * C + c) * N;
    float xf[16];
    if (!edge) {                                      // prefetch before barrier
        const float4 x0 = *(const float4*)(xr + base - 4);
        const float4 x1 = *(const float4*)(xr + base);
        const float4 x2 = *(const float4*)(xr + base + 4);
        const float4 x3 = *(const float4*)(xr + base + 8);
        xf[0]=x0.x; xf[1]=x0.y; xf[2]=x0.z; xf[3]=x0.w;
        xf[4]=x1.x; xf[5]=x1.y; xf[6]=x1.z; xf[7]=x1.w;
        xf[8]=x2.x; xf[9]=x2.y; xf[10]=x2.z; xf[11]=x2.w;
        xf[12]=x3.x; xf[13]=x3.y; xf[14]=x3.z; xf[15]=x3.w;
    }
    __syncthreads();

    // ---- D ----
    {
        float Vr[6];                          // covers every interp tap in window
#pragma unroll
        for (int m = 0; m < 6; ++m) {
            const float* dr = Dw + (2 * seg + m) * 16;
            float a = 0.f;
#pragma unroll
            for (int d = 0; d < DC; ++d) a = fmaf(w[d], dr[d], a);
            Vr[m] = a;
        }
        const float WA[4] = {0.375f, 0.125f, 0.875f, 0.625f};
        float xsv[14], xvf[14];
        if (!edge) {
#pragma unroll
            for (int i = 0; i < 14; ++i) {
                const int r  = (i + 1) & 3;                    // (base-3+i)&3, base%4==0
                const int ma = ((i + 5) >> 2) - 1 + (r >> 1);  // V index rel. tbase
                const float wa = WA[r];
                xsv[i] = (fmaf(wa, Vr[ma], (1.f - wa) * Vr[ma + 1]) - mc) * sc2;
                xvf[i] = xf[1 + i];
            }
        } else {                                       // verified general path
            const int tbase = t0 + 2 * seg - 2;
#pragma unroll
            for (int i = 0; i < 14; ++i) {
                const int j  = base - 3 + i;
                const int ja = (j < 0) ? -j : j;
                const int jr = min(ja, 2 * N - 2 - ja);        // reflect
                const int t  = jr >> 2;
                const int r  = jr & 3;
                const float wa = WA[r];
                int tA = t - 1 + (r >> 1);
                int tB = tA + 1;
                if (tA < 0) { tA = 0; tB = 0; }   // src clipped to 0 -> V[0] exactly
                if (tB > ND - 1) tB = ND - 1;     // src clipped to 1023 -> V[1023]
                const int ia = tA - tbase;
                const int ib = tB - tbase;
                xsv[i] = (wa * Vr[ia] + (1.f - wa) * Vr[ib] - mc) * sc2;
                xvf[i] = xr[jr];
            }
        }
        unsigned short* pcol = phi + c * 8;
#pragma unroll
        for (int li = 0; li < 8; ++li) {
            const float cen = xsv[li + 3];
            float u[KW];
            float s = 0.25f;                  // center tap: d=0 -> loss/4 = 1/4 exactly
            u[3] = 0.25f;
#pragma unroll
            for (int k = 0; k < KW; ++k) {
                if (k == 3) continue;
                const float d = fabsf(xsv[li + k] - cen);     // already * 2/ln2
                const float e = __builtin_amdgcn_exp2f(-d);   // = exp(-2*d_true)
                const float t = 1.f + e;
                const float uk = e * rcpf(t * t);             // = loss/4
                u[k] = uk;
                s += uk;
            }
            const float al = rcpf(s);
            short8 ph;
#pragma unroll
            for (int k = 0; k < KW; ++k) ph[k] = (short)f2bf(u[k] * al * xvf[li + k]);
            ph[7] = 0;                                         // pad slot
            *(short8*)(pcol + (seg * 8 + li) * PLD) = ph;      // one b128 write
        }
    }
    __syncthreads();

    // ---- E: MFMA, swizzled coalesced A-loads, fully unrolled, 16 K-steps ----
    const int lane = tid & 63;
    const int quad = lane >> 4;
    const int rr   = lane & 15;
    const int o0   = seg * 32;

    floatx4 acc00 = {0.f, 0.f, 0.f, 0.f}, acc01 = acc00, acc10 = acc00, acc11 = acc00;
    const short8* wp = (const short8*)wbs + (size_t)seg * (NS * 2 * 64) + lane;
    const unsigned short* prow0 = phi + rr * PLD + quad * 8;
    const unsigned short* prow1 = prow0 + 16 * PLD;

#pragma unroll
    for (int s = 0; s < NS; ++s) {
        const int f0 = 32 * s;
        const short8 a0 = wp[s * 128];          // 64 lanes x 16 B contiguous
        const short8 a1 = wp[s * 128 + 64];
        const short8 b0 = *(const short8*)(prow0 + f0);
        const short8 b1 = *(const short8*)(prow1 + f0);
        acc00 = __builtin_amdgcn_mfma_f32_16x16x32_bf16(a0, b0, acc00, 0, 0, 0);
        acc01 = __builtin_amdgcn_mfma_f32_16x16x32_bf16(a0, b1, acc01, 0, 0, 0);
        acc10 = __builtin_amdgcn_mfma_f32_16x16x32_bf16(a1, b0, acc10, 0, 0, 0);
        acc11 = __builtin_amdgcn_mfma_f32_16x16x32_bf16(a1, b1, acc11, 0, 0, 0);
    }

    float* ob = out + (size_t)(b * CO) * N + l0;
#pragma unroll
    for (int i = 0; i < 4; ++i) {
        const int om = quad * 4 + i;
        ob[(o0 + om) * N      + rr     ] = acc00[i];
        ob[(o0 + om) * N      + 16 + rr] = acc01[i];
        ob[(o0 + 16 + om) * N + rr     ] = acc10[i];
        ob[(o0 + 16 + om) * N + 16 + rr] = acc11[i];
    }
}
} // namespace

extern "C" void kernel_launch(void* const* d_in, const int* in_sizes, int n_in,
                              void* d_out, int out_size, void* d_ws, size_t ws_size,
                              hipStream_t stream)
{
    const float* deep   = (const float*)d_in[0];
    const float* x      = (const float*)d_in[1];
    const float* conv_w = (const float*)d_in[2];
    const float* conv_b = (const float*)d_in[3];
    const float* fc_w   = (const float*)d_in[4];
    float* out = (float*)d_out;

    unsigned short* wbuf = (unsigned short*)((char*)d_ws + WB_OFF);
    float*          gp   = (float*)((char*)d_ws + GP_OFF);
    float*          mcs  = (float*)((char*)d_ws + MC_OFF);
    float*          scs  = (float*)((char*)d_ws + SC_OFF);

    hipLaunchKernelGGL(k0, dim3(32 + 128), dim3(256), 0, stream,
                       deep, fc_w, wbuf, gp);
    hipLaunchKernelGGL(ks, dim3(Bc), dim3(256), 0, stream,
                       gp, conv_w, conv_b, mcs, scs);
    hipLaunchKernelGGL(k2, dim3(N / LT, Bc), dim3(256), 0, stream,
                       deep, conv_w, x, mcs, scs, wbuf, out);
}